// Round 5
// baseline (33.905 us; speedup 1.0000x reference)
//
#include <hip/hip_runtime.h>

#define NSCALE 16

__device__ __forceinline__ float exp2fast(float x) {
#if __has_builtin(__builtin_amdgcn_exp2f)
    return __builtin_amdgcn_exp2f(x);
#else
    return __expf(x * 0.6931471805599453f);
#endif
}
__device__ __forceinline__ float rsqfast(float x) {
#if __has_builtin(__builtin_amdgcn_rsqf)
    return __builtin_amdgcn_rsqf(x);
#else
    return rsqrtf(x);
#endif
}

// Scale groups (s' = global s index + 1; mu_{s'} = C/s' so e_{s'/2} = e_{s'}^2):
//  G0 locals {16,12,8,4,2,1,6,3}: exp for 16,12; rest by repeated squaring
//  G1 locals {9,10,11,13,14,15,5,7}: exp for 9..15 (6x); 5=10^2, 7=14^2
// Pass-2 inverse tables (verified in R4, which passed): g-mask 0x7750,
// local-slot nibbles 0x0543121027663745.

template <int G>
__device__ __forceinline__ void point_body(
    float fi, float px, float py, float pz,
    float ox, float oy, float oz, const float* __restrict__ k, float* __restrict__ acc)
{
    const float dx = px - ox, dy = py - oy, dz = pz - oz;   // SGPR - VGPR
    const float r2 = fmaf(dx, dx, fmaf(dy, dy, dz * dz));
    const float rinv = rsqfast(r2);
    const float r  = r2 * rinv;
    const float fr = fi * rinv;
    const float fx = fr * dx, fy = fr * dy, fz = fr * dz;
    float e[8];
    if constexpr (G == 0) {
        e[0] = exp2fast(k[0] * r); e[1] = exp2fast(k[1] * r);
        e[2] = e[0] * e[0]; e[3] = e[2] * e[2];
        e[4] = e[3] * e[3]; e[5] = e[4] * e[4];
        e[6] = e[1] * e[1]; e[7] = e[6] * e[6];
    } else {
        e[0] = exp2fast(k[0] * r); e[1] = exp2fast(k[1] * r);
        e[2] = exp2fast(k[2] * r); e[3] = exp2fast(k[3] * r);
        e[4] = exp2fast(k[4] * r); e[5] = exp2fast(k[5] * r);
        e[6] = e[1] * e[1];        e[7] = e[4] * e[4];
    }
#pragma unroll
    for (int s = 0; s < 8; ++s) {
        acc[4 * s + 0] = fmaf(e[s], fi, acc[4 * s + 0]);
        acc[4 * s + 1] = fmaf(e[s], fx, acc[4 * s + 1]);
        acc[4 * s + 2] = fmaf(e[s], fy, acc[4 * s + 2]);
        acc[4 * s + 3] = fmaf(e[s], fz, acc[4 * s + 3]);
    }
}

template <int G>
__device__ __forceinline__ void run_range(
    const float* __restrict__ f, const float* __restrict__ coords,
    int i0, int i1, float ox, float oy, float oz,
    const float* __restrict__ k, float* __restrict__ acc)
{
    int t = i0;
    if ((i0 & 3) == 0) {
        const float4* cq = (const float4*)coords;
        const float4* fq = (const float4*)f;
        for (; t + 4 <= i1; t += 4) {
            // wave-uniform indices -> scalar (s_load) fetches into SGPRs
            const float4 fv = fq[t >> 2];
            const int cb = (3 * t) >> 2;
            const float4 c0 = cq[cb + 0];
            const float4 c1 = cq[cb + 1];
            const float4 c2 = cq[cb + 2];
            point_body<G>(fv.x, c0.x, c0.y, c0.z, ox, oy, oz, k, acc);
            point_body<G>(fv.y, c0.w, c1.x, c1.y, ox, oy, oz, k, acc);
            point_body<G>(fv.z, c1.z, c1.w, c2.x, ox, oy, oz, k, acc);
            point_body<G>(fv.w, c2.y, c2.z, c2.w, ox, oy, oz, k, acc);
        }
    }
    for (; t < i1; ++t)
        point_body<G>(f[t], coords[3 * t], coords[3 * t + 1], coords[3 * t + 2],
                      ox, oy, oz, k, acc);
}

// Pass 1: block = (a-tile of 64) x (i-chunk). 8 waves = 2 scale-groups x 4
// i-subsegments. lane = a; acc[32] per lane is the final per-a partial for its
// group -> no cross-lane shuffle at all. 4-wave LDS reduce, chunk partial -> P.
__global__ __launch_bounds__(512, 4) void sph_pass1(
    const float* __restrict__ f, const float* __restrict__ coords,
    const float* __restrict__ out_coords, const float* __restrict__ mu,
    float* __restrict__ P, int N, int A, int AT, int NCH)
{
    __shared__ float lds[2 * 3 * 32 * 64];   // 48 KB

    const int tid  = threadIdx.x;
    const int lane = tid & 63;
    const int w    = __builtin_amdgcn_readfirstlane(tid) >> 6;  // uniform 0..7
    const int g    = w >> 2;
    const int sub  = w & 3;

    const int at = blockIdx.x % AT;
    const int ch = blockIdx.x / AT;

    int a = at * 64 + lane; if (a >= A) a = A - 1;
    const float ox = out_coords[3 * a + 0];
    const float oy = out_coords[3 * a + 1];
    const float oz = out_coords[3 * a + 2];

    const float L2E = 1.44269504088896340736f;
    float k[6];
    if (g == 0) {
        k[0] = -L2E * mu[15]; k[1] = -L2E * mu[11];
        k[2] = k[3] = k[4] = k[5] = 0.f;
    } else {
        k[0] = -L2E * mu[8];  k[1] = -L2E * mu[9];  k[2] = -L2E * mu[10];
        k[3] = -L2E * mu[12]; k[4] = -L2E * mu[13]; k[5] = -L2E * mu[14];
    }

    float acc[32];
#pragma unroll
    for (int v = 0; v < 32; ++v) acc[v] = 0.f;

    const int nseg   = NCH * 4;
    const int seglen = (N + nseg - 1) / nseg;
    const int i0 = (ch * 4 + sub) * seglen;
    const int i1 = min(N, i0 + seglen);

    if (i0 < i1) {
        if (g == 0) run_range<0>(f, coords, i0, i1, ox, oy, oz, k, acc);
        else        run_range<1>(f, coords, i0, i1, ox, oy, oz, k, acc);
    }

    if (sub > 0) {
        float* dst = &lds[((g * 3 + (sub - 1)) * 32) * 64];
#pragma unroll
        for (int v = 0; v < 32; ++v) dst[v * 64 + lane] = acc[v];
    }
    __syncthreads();
    if (sub == 0) {
        const float* base = &lds[(g * 3 * 32) * 64];
        float* Pb = P + ((size_t)(ch * 2 + g) * AT + at) * 2048;
#pragma unroll
        for (int v = 0; v < 32; ++v) {
            const float s = acc[v]
                + base[(0 * 32 + v) * 64 + lane]
                + base[(1 * 32 + v) * 64 + lane]
                + base[(2 * 32 + v) * 64 + lane];
            Pb[v * 64 + lane] = s;   // coalesced 256B per v
        }
    }
}

// Pass 2: sum NCH chunk partials, apply norms, write out[a][64].
__global__ __launch_bounds__(256) void sph_pass2(
    const float* __restrict__ P, const float* __restrict__ r_norms,
    const float* __restrict__ a0, const float* __restrict__ a1,
    float* __restrict__ out, int A, int AT, int CB)
{
    const int tid = blockIdx.x * blockDim.x + threadIdx.x;
    if (tid >= A * 64) return;
    const int a  = tid >> 6;
    const int ov = tid & 63;
    int s, cc;
    if (ov < 16) { s = ov; cc = 0; }
    else { const int q = ov - 16; s = q / 3; cc = q - 3 * s + 1; }
    const int g  = (0x7750 >> s) & 1;
    const int sl = (int)((0x0543121027663745ULL >> (4 * s)) & 15ULL);
    const int v  = 4 * sl + cc;
    const int at = a >> 6, l = a & 63;
    const size_t stride = (size_t)2 * AT * 2048;
    const float* p = P + ((size_t)(g * AT + at)) * 2048 + v * 64 + l;
    float sum = 0.f;
    for (int cb = 0; cb < CB; ++cb) sum += p[(size_t)cb * stride];
    const float scale = r_norms[s] * (cc == 0 ? a0[0] : a1[cc - 1]);
    out[(size_t)a * 64 + ov] = sum * scale;
}

extern "C" void kernel_launch(void* const* d_in, const int* in_sizes, int n_in,
                              void* d_out, int out_size, void* d_ws, size_t ws_size,
                              hipStream_t stream) {
    const float* f          = (const float*)d_in[0];
    const float* coords     = (const float*)d_in[1];
    const float* out_coords = (const float*)d_in[2];
    const float* mu         = (const float*)d_in[3];
    const float* r_norms    = (const float*)d_in[4];
    const float* a_norms_0  = (const float*)d_in[5];
    const float* a_norms_1  = (const float*)d_in[6];
    float* out = (float*)d_out;

    const int N  = in_sizes[0];        // f is [B=1, N]
    const int A  = in_sizes[2] / 3;    // out_coords is [B=1, A, 3]
    const int AT = (A + 63) / 64;

    int NCH = 16;                      // i-chunks; partials = NCH*2*AT*8KB
    while (NCH > 1 && (size_t)NCH * 2 * AT * 2048 * sizeof(float) > ws_size) NCH >>= 1;

    float* P = (float*)d_ws;
    sph_pass1<<<dim3(AT * NCH), 512, 0, stream>>>(f, coords, out_coords, mu,
                                                  P, N, A, AT, NCH);
    const int n2 = A * 64;
    sph_pass2<<<(n2 + 255) / 256, 256, 0, stream>>>(P, r_norms, a_norms_0, a_norms_1,
                                                    out, A, AT, NCH);
}

// Round 6
// 19.448 us; speedup vs baseline: 1.7433x; 1.7433x over previous
//
#include <hip/hip_runtime.h>

typedef float float2v __attribute__((ext_vector_type(2)));

#define LDSPTS 2048

__device__ __forceinline__ float exp2fast(float x) {
#if __has_builtin(__builtin_amdgcn_exp2f)
    return __builtin_amdgcn_exp2f(x);
#else
    return __expf(x * 0.6931471805599453f);
#endif
}
__device__ __forceinline__ float rsqfast(float x) {
#if __has_builtin(__builtin_amdgcn_rsqf)
    return __builtin_amdgcn_rsqf(x);
#else
    return rsqrtf(x);
#endif
}

// One dispatch. Block = 256 thr = 4 waves = 2 output points x 2 i-halves.
// lane = i (within its half, stride 128). Each wave does ALL 16 scales:
// 8 exp seeds (s'=16,12,9,10,11,13,14,15), rest by squaring (mu_s' = C/s' =>
// e_{s'/2} = e_{s'}^2). acc as float2v[32] -> v_pk_fma_f32.
// Points staged once per block into LDS SoA; inner loop reads 4x ds_read_b32
// at immediate offsets. Value-split butterfly (R1-verified mapping: lane l
// ends with float-index l = 4s+c), LDS combine of i-halves, norms in-kernel.
__global__ __launch_bounds__(256, 4) void sph_one(
    const float* __restrict__ f, const float* __restrict__ coords,
    const float* __restrict__ out_coords, const float* __restrict__ mu,
    const float* __restrict__ r_norms, const float* __restrict__ a0,
    const float* __restrict__ a1, float* __restrict__ out, int N, int A)
{
    __shared__ float sF[LDSPTS], sX[LDSPTS], sY[LDSPTS], sZ[LDSPTS];
    __shared__ float red[2][64];

    const int tid  = threadIdx.x;
    const int lane = tid & 63;
    const int w    = tid >> 6;
    const int pa   = w >> 1;      // which output point in block
    const int ih   = w & 1;       // i-half
    const int a    = blockIdx.x * 2 + pa;
    const bool act = (a < A);

    float ox = 0.f, oy = 0.f, oz = 0.f;
    if (act) {
        ox = out_coords[3 * a + 0];
        oy = out_coords[3 * a + 1];
        oz = out_coords[3 * a + 2];
    }

    const float L2E = 1.44269504088896340736f;
    const float k16 = -L2E * mu[15], k12 = -L2E * mu[11];
    const float k9  = -L2E * mu[8],  k10 = -L2E * mu[9],  k11 = -L2E * mu[10];
    const float k13 = -L2E * mu[12], k14 = -L2E * mu[13], k15 = -L2E * mu[14];

    float2v acc2[32];             // float index 4s+c; acc2[2s]={f,fx}, acc2[2s+1]={fy,fz}
#pragma unroll
    for (int j = 0; j < 32; ++j) { acc2[j].x = 0.f; acc2[j].y = 0.f; }

    for (int base = 0; base < N; base += LDSPTS) {
        const int seg = min(LDSPTS, N - base);
        __syncthreads();
        for (int idx = tid; idx < seg; idx += 256) {
            const int gi = base + idx;
            sF[idx] = f[gi];
            sX[idx] = coords[3 * gi + 0];
            sY[idx] = coords[3 * gi + 1];
            sZ[idx] = coords[3 * gi + 2];
        }
        __syncthreads();
        if (act) {
#pragma unroll 2
            for (int t = lane + (ih << 6); t < seg; t += 128) {
                const float fi = sF[t];
                const float dx = sX[t] - ox;
                const float dy = sY[t] - oy;
                const float dz = sZ[t] - oz;
                const float r2 = fmaf(dx, dx, fmaf(dy, dy, dz * dz));
                const float rinv = rsqfast(r2);
                const float r  = r2 * rinv;
                const float fr = fi * rinv;
                float2v v01, v23;
                v01.x = fi;      v01.y = fr * dx;
                v23.x = fr * dy; v23.y = fr * dz;

                float e[16];                  // e[s] for global scale s (s' = s+1)
                e[15] = exp2fast(k16 * r);
                e[11] = exp2fast(k12 * r);
                e[8]  = exp2fast(k9  * r);
                e[9]  = exp2fast(k10 * r);
                e[10] = exp2fast(k11 * r);
                e[12] = exp2fast(k13 * r);
                e[13] = exp2fast(k14 * r);
                e[14] = exp2fast(k15 * r);
                e[7] = e[15] * e[15];         // s'=8
                e[3] = e[7]  * e[7];          // 4
                e[1] = e[3]  * e[3];          // 2
                e[0] = e[1]  * e[1];          // 1
                e[5] = e[11] * e[11];         // 6
                e[2] = e[5]  * e[5];          // 3
                e[4] = e[9]  * e[9];          // 5
                e[6] = e[13] * e[13];         // 7
#pragma unroll
                for (int s = 0; s < 16; ++s) {
                    float2v es; es.x = e[s]; es.y = e[s];
                    acc2[2 * s + 0] = es * v01 + acc2[2 * s + 0];  // v_pk_fma_f32
                    acc2[2 * s + 1] = es * v23 + acc2[2 * s + 1];
                }
            }
        }
    }

    // value-split butterfly: float2 levels (lane masks 32..2), then component level.
#pragma unroll
    for (int m2 = 16; m2 >= 1; m2 >>= 1) {
        const int M = m2 * 2;
        const bool hi = (lane & M) != 0;
#pragma unroll
        for (int j = 0; j < m2; ++j) {
            const float2v lo_v = acc2[j];
            const float2v hi_v = acc2[j + m2];
            float gx = hi ? lo_v.x : hi_v.x;
            float gy = hi ? lo_v.y : hi_v.y;
            const float kx = hi ? hi_v.x : lo_v.x;
            const float ky = hi ? hi_v.y : lo_v.y;
            gx = __shfl_xor(gx, M, 64);
            gy = __shfl_xor(gy, M, 64);
            acc2[j].x = kx + gx;
            acc2[j].y = ky + gy;
        }
    }
    const bool h0 = (lane & 1) != 0;
    const float give = h0 ? acc2[0].x : acc2[0].y;
    const float keep = h0 ? acc2[0].y : acc2[0].x;
    const float tot = keep + __shfl_xor(give, 1, 64);   // lane l holds value 4s+c = l

    if (act && ih == 1) red[pa][lane] = tot;
    __syncthreads();
    if (act && ih == 0) {
        const float sum = tot + red[pa][lane];
        const int s = lane >> 2;
        const int c = lane & 3;
        float scale; int ov;
        if (c == 0) { scale = r_norms[s] * a0[0]; ov = s; }
        else        { scale = r_norms[s] * a1[c - 1]; ov = 16 + 3 * s + (c - 1); }
        out[a * 64 + ov] = sum * scale;
    }
}

extern "C" void kernel_launch(void* const* d_in, const int* in_sizes, int n_in,
                              void* d_out, int out_size, void* d_ws, size_t ws_size,
                              hipStream_t stream) {
    const float* f          = (const float*)d_in[0];
    const float* coords     = (const float*)d_in[1];
    const float* out_coords = (const float*)d_in[2];
    const float* mu         = (const float*)d_in[3];
    const float* r_norms    = (const float*)d_in[4];
    const float* a_norms_0  = (const float*)d_in[5];
    const float* a_norms_1  = (const float*)d_in[6];
    float* out = (float*)d_out;

    const int N = in_sizes[0];       // f is [B=1, N]
    const int A = in_sizes[2] / 3;   // out_coords is [B=1, A, 3]

    sph_one<<<(A + 1) / 2, 256, 0, stream>>>(f, coords, out_coords, mu, r_norms,
                                             a_norms_0, a_norms_1, out, N, A);
}